// Round 9
// baseline (102.048 us; speedup 1.0000x reference)
//
#include <hip/hip_runtime.h>

#define IC 128
#define OC 256
#define RR 64
#define CCOLS 64
#define HO 62
#define WO 62
#define NB 16

// Fragment-major dense bf16 weights:
//   W9Tf[chunk][w][lane][elem], chunk = kp*8+ck (72), w = oc>>5 (8 groups),
//   lane = (oc&31) + 32*khalf (64), elem = c&7 (8 bf16 = 16 B).
// A wave's A-fragment load for one chunk is base + lane*16: 1 KB contiguous.
#define W9T_BYTES (9 * OC * IC * 2)   // 589824
#define CHUNK_STRIDE 8192             // 8 ocgroups * 64 lanes * 16 B
#define LDSROW 16384                  // one image row: 64 x * 256 B

typedef __bf16 bf16x8 __attribute__((ext_vector_type(8)));
typedef float f32x16 __attribute__((ext_vector_type(16)));

__device__ __forceinline__ unsigned short f2bf(float f) {
    unsigned u = __builtin_bit_cast(unsigned, f);
    u += 0x7FFFu + ((u >> 16) & 1u);   // round-to-nearest-even
    return (unsigned short)(u >> 16);
}

__global__ void prep_weights(const float* __restrict__ wv,
                             const int* __restrict__ iwi,
                             const int* __restrict__ flen,
                             const int* __restrict__ sp,
                             unsigned char* __restrict__ W9Tf) {
    const int oc = blockIdx.x;
    const int s = sp[oc];
    const int n = flen[oc];
    const int w = oc >> 5;
    for (int t = threadIdx.x; t < n; t += blockDim.x) {
        const int ix = iwi[s + t];          // c*4096 + ky*64 + kx
        const int c = ix >> 12;
        const int rem = ix & 4095;
        const int ky = rem >> 6, kx = rem & 63;
        const int kp = ky * 3 + kx;
        const int ck = c >> 4;
        const int khalf = (c >> 3) & 1;
        const int lane = (oc & 31) + (khalf << 5);
        const size_t off = (size_t)(kp * 8 + ck) * CHUNK_STRIDE +
                           w * 1024 + lane * 16 + (c & 7) * 2;
        *(unsigned short*)(W9Tf + off) = f2bf(wv[s + t]);
    }
}

__global__ void bias_kernel(const int* __restrict__ bias_index,
                            const float* __restrict__ bias_value,
                            float* __restrict__ bias_dense, int nbias) {
    int t = threadIdx.x;
    if (t < OC) bias_dense[t] = 0.f;
    __syncthreads();
    if (t < nbias) atomicAdd(&bias_dense[bias_index[t]], bias_value[t]);
}

// Block = (b, 2 output rows y0,y0+1) x all 256 oc. 512 threads = 8 waves.
// Wave w: 32 oc (one 32x32 m-frag) x 64 x (2 n-tiles) x 2 y-rows.
// Per K-chunk iteration: 1 coalesced A-load feeds 4 MFMAs (A reused across
// both y-rows) -> 2x latency amortization vs R8 (23% MfmaUtil, 64us).
// LDS: rows y0..y0+3, x-major bf16 [4][64x][128c], XOR-swizzled, 64 KB
// -> 2 blocks/CU; 496 blocks = ~2/CU exactly (no straggler tail).
__global__ __launch_bounds__(512, 2) void conv_mfma(
    const float* __restrict__ images,
    const unsigned char* __restrict__ W9Tf,
    const float* __restrict__ bias_dense,
    float* __restrict__ out)
{
    const int y0 = blockIdx.x * 2;
    const int b = blockIdx.y;
    const int t = threadIdx.x;
    const int w = t >> 6;
    const int l = t & 63;
    const int lm = l & 31;            // m-row / n-col within frag
    const int lhi = l >> 5;           // k-half

    __shared__ unsigned char lds[4 * LDSROW];   // 65536 B

    const float* __restrict__ imgb = images + (size_t)b * (IC * RR * CCOLS);

    // ---- stage 4 image rows, fp32 -> bf16, [x][c] with XOR swizzle ----
    {
        const int xs = t & 63;
        const int oct = t >> 6;             // 0..7
        const int swz = (xs & 7) << 4;
        #pragma unroll
        for (int krow = 0; krow < 4; ++krow) {
            #pragma unroll
            for (int h = 0; h < 2; ++h) {
                const int c0 = (oct + 8 * h) * 8;   // octet base channel
                const float* __restrict__ p =
                    imgb + (size_t)c0 * (RR * CCOLS) + (y0 + krow) * CCOLS + xs;
                unsigned v0, v1, v2, v3;
                v0 = (unsigned)f2bf(p[0])              | ((unsigned)f2bf(p[RR * CCOLS])     << 16);
                v1 = (unsigned)f2bf(p[2 * RR * CCOLS]) | ((unsigned)f2bf(p[3 * RR * CCOLS]) << 16);
                v2 = (unsigned)f2bf(p[4 * RR * CCOLS]) | ((unsigned)f2bf(p[5 * RR * CCOLS]) << 16);
                v3 = (unsigned)f2bf(p[6 * RR * CCOLS]) | ((unsigned)f2bf(p[7 * RR * CCOLS]) << 16);
                *(uint4*)(lds + krow * LDSROW + xs * 256 + ((c0 * 2) ^ swz)) =
                    make_uint4(v0, v1, v2, v3);
            }
        }
    }

    // lane's coalesced A base
    const unsigned char* __restrict__ pA = W9Tf + w * 1024 + l * 16;

    // prologue: prefetch A chunks 0..2 (global only, no LDS hazard)
    bf16x8 aC  = *(const bf16x8*)(pA);
    bf16x8 aN1 = *(const bf16x8*)(pA + CHUNK_STRIDE);
    bf16x8 aN2 = *(const bf16x8*)(pA + 2 * CHUNK_STRIDE);

    __syncthreads();

    // named accumulators (static indexing -> no scratch; rule #20)
    f32x16 acc00 = {}, acc01 = {}, acc10 = {}, acc11 = {};

    #pragma unroll
    for (int idx = 0; idx < 72; ++idx) {
        const int kp = idx >> 3, ck = idx & 7;           // compile-time
        const int ky = kp / 3, kx = kp % 3;

        // prefetch A chunk idx+3 (coalesced 1 KB global load)
        bf16x8 aN3;
        if (idx + 3 < 72)
            aN3 = *(const bf16x8*)(pA + (size_t)(idx + 3) * CHUNK_STRIDE);

        // B byte offsets within a 16 KB LDS row (swizzle XOR-composable:
        // ck*32, lhi*16, (x&7)<<4 are disjoint-or-XOR bits; validated R8)
        const int x0 = lm + kx;                          // <= 33, in-bounds
        int x1 = 32 + lm + kx;
        x1 = x1 > 63 ? 63 : x1;   // pad lanes: dup col 63 (output discarded)
        const int pb0 = (x0 * 256 + ((lhi * 16) ^ ((x0 & 7) << 4))) ^ (ck * 32);
        const int pb1 = (x1 * 256 + ((lhi * 16) ^ ((x1 & 7) << 4))) ^ (ck * 32);

        const unsigned char* __restrict__ row0 = lds + (ky + 0) * LDSROW;
        const unsigned char* __restrict__ row1 = lds + (ky + 1) * LDSROW;
        const bf16x8 b00 = *(const bf16x8*)(row0 + pb0);
        const bf16x8 b01 = *(const bf16x8*)(row0 + pb1);
        const bf16x8 b10 = *(const bf16x8*)(row1 + pb0);
        const bf16x8 b11 = *(const bf16x8*)(row1 + pb1);

        acc00 = __builtin_amdgcn_mfma_f32_32x32x16_bf16(aC, b00, acc00, 0, 0, 0);
        acc01 = __builtin_amdgcn_mfma_f32_32x32x16_bf16(aC, b01, acc01, 0, 0, 0);
        acc10 = __builtin_amdgcn_mfma_f32_32x32x16_bf16(aC, b10, acc10, 0, 0, 0);
        acc11 = __builtin_amdgcn_mfma_f32_32x32x16_bf16(aC, b11, acc11, 0, 0, 0);

        aC = aN1; aN1 = aN2; aN2 = aN3;          // SSA-renamed, no copies
    }

    // ---- epilogue: bias + store ----
    // C/D 32x32: col = lane&31, row = (reg&3) + 8*(reg>>2) + 4*(lane>>5)
    const int ocw = 32 * w;
    #pragma unroll
    for (int r = 0; r < 16; ++r) {
        const int oc = ocw + (r & 3) + 8 * (r >> 2) + 4 * lhi;
        const float bv = bias_dense[oc];
        const size_t ob0 = (((size_t)b * OC + oc) * HO + y0) * WO;
        out[ob0 + lm] = acc00[r] + bv;               // x = lm < 62 always
        if (lm < 30)
            out[ob0 + 32 + lm] = acc01[r] + bv;      // x = 32+lm, clip at 62
        const size_t ob1 = ob0 + WO;                 // row y0+1
        out[ob1 + lm] = acc10[r] + bv;
        if (lm < 30)
            out[ob1 + 32 + lm] = acc11[r] + bv;
    }
}

extern "C" void kernel_launch(void* const* d_in, const int* in_sizes, int n_in,
                              void* d_out, int out_size, void* d_ws, size_t ws_size,
                              hipStream_t stream) {
    const float* images             = (const float*)d_in[0];
    const float* weight_value       = (const float*)d_in[1];
    const int*   image_weight_index = (const int*)d_in[2];
    const int*   filter_lengths     = (const int*)d_in[3];
    const int*   start_points       = (const int*)d_in[4];
    const int*   bias_index         = (const int*)d_in[5];
    const float* bias_value         = (const float*)d_in[6];
    float* out = (float*)d_out;

    unsigned char* W9Tf = (unsigned char*)d_ws;
    float* bias_dense = (float*)((char*)d_ws + W9T_BYTES);

    hipMemsetAsync(d_ws, 0, W9T_BYTES, stream);
    prep_weights<<<OC, 256, 0, stream>>>(weight_value, image_weight_index,
                                         filter_lengths, start_points, W9Tf);
    bias_kernel<<<1, 256, 0, stream>>>(bias_index, bias_value, bias_dense,
                                       in_sizes[5]);

    dim3 grid(HO / 2, NB);
    conv_mfma<<<grid, 512, 0, stream>>>(images, W9Tf, bias_dense, out);
}

// Round 10
// 91.078 us; speedup vs baseline: 1.1205x; 1.1205x over previous
//
#include <hip/hip_runtime.h>

#define IC 128
#define OC 256
#define RR 64
#define CCOLS 64
#define HO 62
#define WO 62
#define NB 16

// Fragment-major dense bf16 weights:
//   W9Tf[chunk][w][lane][elem], chunk = kp*8+ck (72), w = oc>>5 (8 groups),
//   lane = (oc&31) + 32*khalf (64), elem = c&7 (8 bf16 = 16 B).
// A wave's A-fragment load for one chunk is base + lane*16: 1 KB contiguous.
#define W9T_BYTES (9 * OC * IC * 2)   // 589824
#define CHUNK_STRIDE 8192             // 8 ocgroups * 64 lanes * 16 B
#define LDSROW 16384                  // one image row: 64 x * 256 B

typedef __bf16 bf16x8 __attribute__((ext_vector_type(8)));
typedef float f32x16 __attribute__((ext_vector_type(16)));

__device__ __forceinline__ unsigned short f2bf(float f) {
    unsigned u = __builtin_bit_cast(unsigned, f);
    u += 0x7FFFu + ((u >> 16) & 1u);   // round-to-nearest-even
    return (unsigned short)(u >> 16);
}

__global__ void prep_weights(const float* __restrict__ wv,
                             const int* __restrict__ iwi,
                             const int* __restrict__ flen,
                             const int* __restrict__ sp,
                             unsigned char* __restrict__ W9Tf) {
    const int oc = blockIdx.x;
    const int s = sp[oc];
    const int n = flen[oc];
    const int w = oc >> 5;
    for (int t = threadIdx.x; t < n; t += blockDim.x) {
        const int ix = iwi[s + t];          // c*4096 + ky*64 + kx
        const int c = ix >> 12;
        const int rem = ix & 4095;
        const int ky = rem >> 6, kx = rem & 63;
        const int kp = ky * 3 + kx;
        const int ck = c >> 4;
        const int khalf = (c >> 3) & 1;
        const int lane = (oc & 31) + (khalf << 5);
        const size_t off = (size_t)(kp * 8 + ck) * CHUNK_STRIDE +
                           w * 1024 + lane * 16 + (c & 7) * 2;
        *(unsigned short*)(W9Tf + off) = f2bf(wv[s + t]);
    }
}

__global__ void bias_kernel(const int* __restrict__ bias_index,
                            const float* __restrict__ bias_value,
                            float* __restrict__ bias_dense, int nbias) {
    int t = threadIdx.x;
    if (t < OC) bias_dense[t] = 0.f;
    __syncthreads();
    if (t < nbias) atomicAdd(&bias_dense[bias_index[t]], bias_value[t]);
}

// Block = (b, 2 output rows y0,y0+1) x all 256 oc. 512 threads = 8 waves.
// Wave w: 32 oc (one 32x32 m-frag) x 64 x (2 n-tiles) x 2 y-rows.
// Per K-chunk iteration: 1 coalesced A-load feeds 4 MFMAs; B prefetched
// 1 chunk deep (LDS latency covered), A 3 deep (L2 latency covered).
// launch_bounds(512,1): reg cap 256. R9's (512,2) clamped at 128 and
// spilled the 140-reg demand (WRITE_SIZE 156MB); accepting 8 waves/CU
// (2/SIMD) with 4-deep per-wave ILP instead.
__global__ __launch_bounds__(512, 1) void conv_mfma(
    const float* __restrict__ images,
    const unsigned char* __restrict__ W9Tf,
    const float* __restrict__ bias_dense,
    float* __restrict__ out)
{
    const int y0 = blockIdx.x * 2;
    const int b = blockIdx.y;
    const int t = threadIdx.x;
    const int w = t >> 6;
    const int l = t & 63;
    const int lm = l & 31;            // m-row / n-col within frag
    const int lhi = l >> 5;           // k-half

    __shared__ unsigned char lds[4 * LDSROW];   // 65536 B

    const float* __restrict__ imgb = images + (size_t)b * (IC * RR * CCOLS);

    // ---- stage 4 image rows, fp32 -> bf16, [x][c] with XOR swizzle ----
    {
        const int xs = t & 63;
        const int oct = t >> 6;             // 0..7
        const int swz = (xs & 7) << 4;
        #pragma unroll
        for (int krow = 0; krow < 4; ++krow) {
            #pragma unroll
            for (int h = 0; h < 2; ++h) {
                const int c0 = (oct + 8 * h) * 8;   // octet base channel
                const float* __restrict__ p =
                    imgb + (size_t)c0 * (RR * CCOLS) + (y0 + krow) * CCOLS + xs;
                unsigned v0, v1, v2, v3;
                v0 = (unsigned)f2bf(p[0])              | ((unsigned)f2bf(p[RR * CCOLS])     << 16);
                v1 = (unsigned)f2bf(p[2 * RR * CCOLS]) | ((unsigned)f2bf(p[3 * RR * CCOLS]) << 16);
                v2 = (unsigned)f2bf(p[4 * RR * CCOLS]) | ((unsigned)f2bf(p[5 * RR * CCOLS]) << 16);
                v3 = (unsigned)f2bf(p[6 * RR * CCOLS]) | ((unsigned)f2bf(p[7 * RR * CCOLS]) << 16);
                *(uint4*)(lds + krow * LDSROW + xs * 256 + ((c0 * 2) ^ swz)) =
                    make_uint4(v0, v1, v2, v3);
            }
        }
    }

    // lane's coalesced A base
    const unsigned char* __restrict__ pA = W9Tf + w * 1024 + l * 16;

    // prologue: prefetch A chunks 0..2 (global only, no LDS hazard)
    bf16x8 aC  = *(const bf16x8*)(pA);
    bf16x8 aN1 = *(const bf16x8*)(pA + CHUNK_STRIDE);
    bf16x8 aN2 = *(const bf16x8*)(pA + 2 * CHUNK_STRIDE);

    __syncthreads();

    // B reader for chunk idx (compile-time ky/kx/ck under full unroll)
    auto readB = [&](int idx, bf16x8& b00, bf16x8& b01, bf16x8& b10, bf16x8& b11) {
        const int kp = idx >> 3, ck = idx & 7;
        const int ky = kp / 3, kx = kp % 3;
        const int x0 = lm + kx;                      // <= 33, in-bounds
        int x1 = 32 + lm + kx;
        x1 = x1 > 63 ? 63 : x1;   // pad lanes: dup col 63 (output discarded)
        const int pb0 = (x0 * 256 + ((lhi * 16) ^ ((x0 & 7) << 4))) ^ (ck * 32);
        const int pb1 = (x1 * 256 + ((lhi * 16) ^ ((x1 & 7) << 4))) ^ (ck * 32);
        const unsigned char* __restrict__ row0 = lds + (ky + 0) * LDSROW;
        const unsigned char* __restrict__ row1 = lds + (ky + 1) * LDSROW;
        b00 = *(const bf16x8*)(row0 + pb0);
        b01 = *(const bf16x8*)(row0 + pb1);
        b10 = *(const bf16x8*)(row1 + pb0);
        b11 = *(const bf16x8*)(row1 + pb1);
    };

    // named accumulators (static indexing -> no scratch; rule #20)
    f32x16 acc00 = {}, acc01 = {}, acc10 = {}, acc11 = {};
    bf16x8 b00c, b01c, b10c, b11c;
    readB(0, b00c, b01c, b10c, b11c);

    #pragma unroll
    for (int idx = 0; idx < 72; ++idx) {
        // prefetch A chunk idx+3 (coalesced 1 KB global load)
        bf16x8 aN3;
        if (idx + 3 < 72)
            aN3 = *(const bf16x8*)(pA + (size_t)(idx + 3) * CHUNK_STRIDE);
        // prefetch B chunk idx+1 (4x ds_read_b128, covered by MFMAs below)
        bf16x8 b00n, b01n, b10n, b11n;
        if (idx + 1 < 72) readB(idx + 1, b00n, b01n, b10n, b11n);

        acc00 = __builtin_amdgcn_mfma_f32_32x32x16_bf16(aC, b00c, acc00, 0, 0, 0);
        acc01 = __builtin_amdgcn_mfma_f32_32x32x16_bf16(aC, b01c, acc01, 0, 0, 0);
        acc10 = __builtin_amdgcn_mfma_f32_32x32x16_bf16(aC, b10c, acc10, 0, 0, 0);
        acc11 = __builtin_amdgcn_mfma_f32_32x32x16_bf16(aC, b11c, acc11, 0, 0, 0);

        aC = aN1; aN1 = aN2; aN2 = aN3;          // SSA-renamed, no copies
        if (idx + 1 < 72) { b00c = b00n; b01c = b01n; b10c = b10n; b11c = b11n; }
    }

    // ---- epilogue: bias + store ----
    // C/D 32x32: col = lane&31, row = (reg&3) + 8*(reg>>2) + 4*(lane>>5)
    const int ocw = 32 * w;
    #pragma unroll
    for (int r = 0; r < 16; ++r) {
        const int oc = ocw + (r & 3) + 8 * (r >> 2) + 4 * lhi;
        const float bv = bias_dense[oc];
        const size_t ob0 = (((size_t)b * OC + oc) * HO + y0) * WO;
        out[ob0 + lm] = acc00[r] + bv;               // x = lm < 62 always
        if (lm < 30)
            out[ob0 + 32 + lm] = acc01[r] + bv;      // x = 32+lm, clip at 62
        const size_t ob1 = ob0 + WO;                 // row y0+1
        out[ob1 + lm] = acc10[r] + bv;
        if (lm < 30)
            out[ob1 + 32 + lm] = acc11[r] + bv;
    }
}

extern "C" void kernel_launch(void* const* d_in, const int* in_sizes, int n_in,
                              void* d_out, int out_size, void* d_ws, size_t ws_size,
                              hipStream_t stream) {
    const float* images             = (const float*)d_in[0];
    const float* weight_value       = (const float*)d_in[1];
    const int*   image_weight_index = (const int*)d_in[2];
    const int*   filter_lengths     = (const int*)d_in[3];
    const int*   start_points       = (const int*)d_in[4];
    const int*   bias_index         = (const int*)d_in[5];
    const float* bias_value         = (const float*)d_in[6];
    float* out = (float*)d_out;

    unsigned char* W9Tf = (unsigned char*)d_ws;
    float* bias_dense = (float*)((char*)d_ws + W9T_BYTES);

    hipMemsetAsync(d_ws, 0, W9T_BYTES, stream);
    prep_weights<<<OC, 256, 0, stream>>>(weight_value, image_weight_index,
                                         filter_lengths, start_points, W9Tf);
    bias_kernel<<<1, 256, 0, stream>>>(bias_index, bias_value, bias_dense,
                                       in_sizes[5]);

    dim3 grid(HO / 2, NB);
    conv_mfma<<<grid, 512, 0, stream>>>(images, W9Tf, bias_dense, out);
}

// Round 11
// 83.949 us; speedup vs baseline: 1.2156x; 1.0849x over previous
//
#include <hip/hip_runtime.h>

#define IC 128
#define OC 256
#define RR 64
#define CCOLS 64
#define HO 62
#define WO 62
#define NB 16

// Fragment-major dense bf16 weights:
//   W9Tf[chunk][g][lane][elem], chunk = kp*8+ck (72), g = oc>>5 (8 groups),
//   lane = (oc&31) + 32*khalf (64), elem = c&7 (8 bf16 = 16 B).
// A wave's A-fragment load for one chunk/group is base + lane*16: 1 KB
// contiguous (coalesced; the R8 win).
#define W9T_BYTES (9 * OC * IC * 2)   // 589824
#define CHUNK_STRIDE 8192             // 8 ocgroups * 64 lanes * 16 B
#define LDSROW 16384                  // one image row: 64 x * 256 B

typedef __bf16 bf16x8 __attribute__((ext_vector_type(8)));
typedef float f32x16 __attribute__((ext_vector_type(16)));

__device__ __forceinline__ unsigned short f2bf(float f) {
    unsigned u = __builtin_bit_cast(unsigned, f);
    u += 0x7FFFu + ((u >> 16) & 1u);   // round-to-nearest-even
    return (unsigned short)(u >> 16);
}

__global__ void prep_weights(const float* __restrict__ wv,
                             const int* __restrict__ iwi,
                             const int* __restrict__ flen,
                             const int* __restrict__ sp,
                             unsigned char* __restrict__ W9Tf) {
    const int oc = blockIdx.x;
    const int s = sp[oc];
    const int n = flen[oc];
    const int g = oc >> 5;
    for (int t = threadIdx.x; t < n; t += blockDim.x) {
        const int ix = iwi[s + t];          // c*4096 + ky*64 + kx
        const int c = ix >> 12;
        const int rem = ix & 4095;
        const int ky = rem >> 6, kx = rem & 63;
        const int kp = ky * 3 + kx;
        const int ck = c >> 4;
        const int khalf = (c >> 3) & 1;
        const int lane = (oc & 31) + (khalf << 5);
        const size_t off = (size_t)(kp * 8 + ck) * CHUNK_STRIDE +
                           g * 1024 + lane * 16 + (c & 7) * 2;
        *(unsigned short*)(W9Tf + off) = f2bf(wv[s + t]);
    }
}

__global__ void bias_kernel(const int* __restrict__ bias_index,
                            const float* __restrict__ bias_value,
                            float* __restrict__ bias_dense, int nbias) {
    int t = threadIdx.x;
    if (t < OC) bias_dense[t] = 0.f;
    __syncthreads();
    if (t < nbias) atomicAdd(&bias_dense[bias_index[t]], bias_value[t]);
}

// Block = one output row (b, y) x all 256 oc. 256 threads = 4 waves.
// Wave w: 64 oc (2 oc-groups: 2w, 2w+1) x 64 x (2 n-tiles): per K-chunk
// iteration = 2 coalesced A-loads + 2 ds_reads + 4 independent MFMAs
// (2x MFMA per LDS byte and 2x per-wave ILP vs R8's 64us/23% config).
// 4-wave block: min-waves/EU is genuinely 1 -> 512-reg ceiling; the 8-wave
// blocks of R9/R10 forced >=2 waves/EU and clamped VGPR at 128 -> spill.
// LDS: rows y..y+2, x-major bf16 [3][64x][128c], XOR-swizzled, 48 KB.
__global__ __launch_bounds__(256, 1) void conv_mfma(
    const float* __restrict__ images,
    const unsigned char* __restrict__ W9Tf,
    const float* __restrict__ bias_dense,
    float* __restrict__ out)
{
    const int y = blockIdx.x;
    const int b = blockIdx.y;
    const int t = threadIdx.x;
    const int w = t >> 6;             // 0..3
    const int l = t & 63;
    const int lm = l & 31;            // m-row / n-col within frag
    const int lhi = l >> 5;           // k-half

    __shared__ unsigned char lds[3 * LDSROW];   // 49152 B

    const float* __restrict__ imgb = images + (size_t)b * (IC * RR * CCOLS);

    // ---- stage 3 image rows, fp32 -> bf16, [x][c] with XOR swizzle ----
    // 256 threads: thread t stages x = t&63, 4 channel-octets (t>>6 + 4h).
    {
        const int xs = t & 63;
        const int og = t >> 6;              // 0..3
        const int swz = (xs & 7) << 4;
        #pragma unroll
        for (int krow = 0; krow < 3; ++krow) {
            #pragma unroll
            for (int h = 0; h < 4; ++h) {
                const int c0 = (og + 4 * h) * 8;    // octet base channel
                const float* __restrict__ p =
                    imgb + (size_t)c0 * (RR * CCOLS) + (y + krow) * CCOLS + xs;
                unsigned v0, v1, v2, v3;
                v0 = (unsigned)f2bf(p[0])              | ((unsigned)f2bf(p[RR * CCOLS])     << 16);
                v1 = (unsigned)f2bf(p[2 * RR * CCOLS]) | ((unsigned)f2bf(p[3 * RR * CCOLS]) << 16);
                v2 = (unsigned)f2bf(p[4 * RR * CCOLS]) | ((unsigned)f2bf(p[5 * RR * CCOLS]) << 16);
                v3 = (unsigned)f2bf(p[6 * RR * CCOLS]) | ((unsigned)f2bf(p[7 * RR * CCOLS]) << 16);
                *(uint4*)(lds + krow * LDSROW + xs * 256 + ((c0 * 2) ^ swz)) =
                    make_uint4(v0, v1, v2, v3);
            }
        }
    }

    // lane's coalesced A bases for the wave's two oc-groups
    const unsigned char* __restrict__ pA0 = W9Tf + (2 * w + 0) * 1024 + l * 16;
    const unsigned char* __restrict__ pA1 = W9Tf + (2 * w + 1) * 1024 + l * 16;

    // prologue: prefetch A chunks 0..2 for both groups (global, no hazard)
    bf16x8 a0C  = *(const bf16x8*)(pA0);
    bf16x8 a1C  = *(const bf16x8*)(pA1);
    bf16x8 a0N1 = *(const bf16x8*)(pA0 + CHUNK_STRIDE);
    bf16x8 a1N1 = *(const bf16x8*)(pA1 + CHUNK_STRIDE);
    bf16x8 a0N2 = *(const bf16x8*)(pA0 + 2 * CHUNK_STRIDE);
    bf16x8 a1N2 = *(const bf16x8*)(pA1 + 2 * CHUNK_STRIDE);

    __syncthreads();

    // B reader for chunk idx (compile-time ky/kx/ck under full unroll)
    auto readB = [&](int idx, bf16x8& b0, bf16x8& b1) {
        const int kp = idx >> 3, ck = idx & 7;
        const int ky = kp / 3, kx = kp % 3;
        const int x0 = lm + kx;                      // <= 33, in-bounds
        int x1 = 32 + lm + kx;
        x1 = x1 > 63 ? 63 : x1;   // pad lanes: dup col 63 (output discarded)
        const unsigned char* __restrict__ row = lds + ky * LDSROW;
        const int pb0 = (x0 * 256 + ((lhi * 16) ^ ((x0 & 7) << 4))) ^ (ck * 32);
        const int pb1 = (x1 * 256 + ((lhi * 16) ^ ((x1 & 7) << 4))) ^ (ck * 32);
        b0 = *(const bf16x8*)(row + pb0);
        b1 = *(const bf16x8*)(row + pb1);
    };

    // named accumulators (static indexing -> no scratch; rule #20)
    f32x16 acc00 = {}, acc01 = {}, acc10 = {}, acc11 = {};  // [m][n]
    bf16x8 b0c, b1c;
    readB(0, b0c, b1c);

    #pragma unroll
    for (int idx = 0; idx < 72; ++idx) {
        // prefetch A chunk idx+3 for both groups (coalesced 1 KB loads)
        bf16x8 a0N3, a1N3;
        if (idx + 3 < 72) {
            a0N3 = *(const bf16x8*)(pA0 + (size_t)(idx + 3) * CHUNK_STRIDE);
            a1N3 = *(const bf16x8*)(pA1 + (size_t)(idx + 3) * CHUNK_STRIDE);
        }
        // prefetch B chunk idx+1 (2x ds_read_b128, covered by MFMAs below)
        bf16x8 b0n, b1n;
        if (idx + 1 < 72) readB(idx + 1, b0n, b1n);

        acc00 = __builtin_amdgcn_mfma_f32_32x32x16_bf16(a0C, b0c, acc00, 0, 0, 0);
        acc10 = __builtin_amdgcn_mfma_f32_32x32x16_bf16(a1C, b0c, acc10, 0, 0, 0);
        acc01 = __builtin_amdgcn_mfma_f32_32x32x16_bf16(a0C, b1c, acc01, 0, 0, 0);
        acc11 = __builtin_amdgcn_mfma_f32_32x32x16_bf16(a1C, b1c, acc11, 0, 0, 0);

        a0C = a0N1; a0N1 = a0N2; a0N2 = a0N3;    // SSA-renamed, no copies
        a1C = a1N1; a1N1 = a1N2; a1N2 = a1N3;
        if (idx + 1 < 72) { b0c = b0n; b1c = b1n; }
    }

    // ---- epilogue: bias + store ----
    // C/D 32x32: col = lane&31, row = (reg&3) + 8*(reg>>2) + 4*(lane>>5)
    #pragma unroll
    for (int m = 0; m < 2; ++m) {
        const int ocw = (2 * w + m) * 32;
        const f32x16 aN0 = m ? acc10 : acc00;
        const f32x16 aN1v = m ? acc11 : acc01;
        #pragma unroll
        for (int r = 0; r < 16; ++r) {
            const int oc = ocw + (r & 3) + 8 * (r >> 2) + 4 * lhi;
            const float bv = bias_dense[oc];
            const size_t ob = (((size_t)b * OC + oc) * HO + y) * WO;
            out[ob + lm] = aN0[r] + bv;              // x = lm < 62 always
            if (lm < 30)
                out[ob + 32 + lm] = aN1v[r] + bv;    // x = 32+lm, clip at 62
        }
    }
}

extern "C" void kernel_launch(void* const* d_in, const int* in_sizes, int n_in,
                              void* d_out, int out_size, void* d_ws, size_t ws_size,
                              hipStream_t stream) {
    const float* images             = (const float*)d_in[0];
    const float* weight_value       = (const float*)d_in[1];
    const int*   image_weight_index = (const int*)d_in[2];
    const int*   filter_lengths     = (const int*)d_in[3];
    const int*   start_points       = (const int*)d_in[4];
    const int*   bias_index         = (const int*)d_in[5];
    const float* bias_value         = (const float*)d_in[6];
    float* out = (float*)d_out;

    unsigned char* W9Tf = (unsigned char*)d_ws;
    float* bias_dense = (float*)((char*)d_ws + W9T_BYTES);

    hipMemsetAsync(d_ws, 0, W9T_BYTES, stream);
    prep_weights<<<OC, 256, 0, stream>>>(weight_value, image_weight_index,
                                         filter_lengths, start_points, W9Tf);
    bias_kernel<<<1, 256, 0, stream>>>(bias_index, bias_value, bias_dense,
                                       in_sizes[5]);

    dim3 grid(HO, NB);
    conv_mfma<<<grid, 256, 0, stream>>>(images, W9Tf, bias_dense, out);
}